// Round 6
// baseline (263.006 us; speedup 1.0000x reference)
//
#include <hip/hip_runtime.h>
#include <stdint.h>

// sample_and_group: B=8 N=8192 C=64 S=2048 K=32 OUT=128
// out = (out[8,2048,128], sampled_coor[8,2048,3]) concatenated in d_out (float32).
//
// R19 (on top of R18's spill fix, which took total 296->245.6):
//  - kknn pass 3: wave-aggregated ballot compaction replaces per-lane
//    atomicAdd-with-return (each LDS atomic return = serialized lgkm wait).
//    Each wave owns cands[w*48..w*48+47]; offset = SGPR wbase + mbcnt(ballot);
//    wbase += popcount (uniform, stays scalar). ZERO LDS atomics.
//  - kknn pass 4: sentinel fixed-bound rank scan. cands slots init ~0ULL
//    (sentinel never < key), scan all 192 slots unrolled x8 -> pipelined
//    ds_reads instead of ~55 dependent 60-cyc load->wait->cmp round trips.
//    Rank-exact: ranks of real candidates are a permutation of 0..E-1.
//  - kphase: GPB 8->16 (1024 blocks): halves per-block prologue/launch
//    overhead in the latency-bound regime. kred1 now sums 16 rows/block.
//  Distance math, threshold logic (T = max over waves of 8th-smallest
//  thread-min), and all kphase math unchanged -> numerics identical.
//
// Workspace layout (bytes):
//   [0,2MB)        knn indices  int32[16384*32]
//   [2MB,10MB)     m = max_k y2 f32[16384*128]
//   [10MB,11MB)    soa coords  f32[8][3][8192] (ALIASES part1; kknn-only lifetime)
//   [10MB,12MB)    partials1    f32[1024*256]
//   [12MB,14MB)    partials2    f32[1024*256]
//   [14MB,+32KB)   w1b  bf16 [o][k=0..127]
//   [..,+32KB)     w2b  bf16 [o][k=0..127]
//   [..,+1KB)      stats1 (scale[128], shift[128])
//   [..,+1KB)      stats2
//   [..,+128KB)    dbuf f64[64*256] (reduce stage-1 output)

#define N_    8192
#define GPB_  16      // groups per block in phase kernels

typedef __attribute__((ext_vector_type(8))) short bf8;
typedef __attribute__((ext_vector_type(16))) float f32x16;
typedef __attribute__((ext_vector_type(2))) float f32x2;

__device__ __forceinline__ unsigned int bf1u(float f) {   // RNE fp32->bf16 bits
  unsigned int u = __float_as_uint(f);
  return (u + 0x7fffu + ((u >> 16) & 1u)) >> 16;
}
__device__ __forceinline__ unsigned int bfpair(float lo, float hi) {
  return bf1u(lo) | (bf1u(hi) << 16);
}

// packed fp32 VOP3P helpers (CDNA: 2x fp32 per instruction, IEEE RN per lane)
__device__ __forceinline__ f32x2 pk_add(f32x2 a, f32x2 b) {
  f32x2 d;
  asm("v_pk_add_f32 %0, %1, %2" : "=v"(d) : "v"(a), "v"(b));
  return d;
}
__device__ __forceinline__ f32x2 pk_mul(f32x2 a, f32x2 b) {
  f32x2 d;
  asm("v_pk_mul_f32 %0, %1, %2" : "=v"(d) : "v"(a), "v"(b));
  return d;
}

// ---------------- prep: weight layouts + SoA coord pack + sampled_coor -------
__global__ __launch_bounds__(256) void kprep(const float* __restrict__ w1,
                                             const float* __restrict__ w2,
                                             const float* __restrict__ coor,
                                             const int* __restrict__ indx,
                                             unsigned short* __restrict__ w1b,
                                             unsigned short* __restrict__ w2b,
                                             float* __restrict__ outc,
                                             float* __restrict__ soa) {
  int e = blockIdx.x * 256 + threadIdx.x;   // grid is exactly 576*256 = 147456
  if (e < 16384) {                           // w1b[o][k] = bf16(w1[o][k])
    w1b[e] = (unsigned short)bf1u(w1[e]);
  } else if (e < 32768) {                    // w2b[o][k] = bf16(w2[o][k])
    int e2 = e - 16384;
    w2b[e2] = (unsigned short)bf1u(w2[e2]);
  } else if (e < 81920) {
    int e2 = e - 32768;                      // 0..49151 sampled_coor
    int bs = e2 / 3, c = e2 - bs * 3;
    int b = bs >> 11, s = bs & 2047;
    outc[e2] = coor[(b * N_ + indx[s]) * 3 + c];
  } else {
    int p = e - 81920;                       // 0..65535 SoA pack
    const int b = p >> 13, i = p & 8191;
    const float* src = coor + (size_t)p * 3;
    float* dst = soa + b * 24576;
    dst[i]         = src[0];
    dst[8192 + i]  = src[1];
    dst[16384 + i] = src[2];
  }
}

// ---------------- KNN: threshold-select, one query per 256-thread block -------
// Output = SET of 32 smallest keys (dist_bits<<32 | idx); order arbitrary
// (downstream max/mean/var are permutation-invariant over K).
// dist[macro 0..3] in registers, macro 4..7 in LDS; NO recompute.
__global__ __launch_bounds__(256, 8) void kknn(const float* __restrict__ soa,
                                               const int* __restrict__ indx,
                                               int* __restrict__ knn) {
  __shared__ __align__(16) float4 sdist4[4 * 256];  // 16KB: dist[it-4][tid] x4
  __shared__ float sTw[4];                    // per-wave 8th-smallest thread-min
  __shared__ unsigned long long cands[192];   // 4 waves x 48-slot regions

  const int gid = blockIdx.x;
  const int b = gid >> 11, s = gid & 2047;
  const int tid = threadIdx.x;
  const int w = tid >> 6, lane = tid & 63;
  const float* Xb = soa + b * 24576;
  const float* Yb = Xb + 8192;
  const float* Zb = Xb + 16384;
  const int qi = indx[s];
  const float qx = Xb[qi], qy = Yb[qi], qz = Zb[qi];
  const f32x2 nqx = {-qx, -qx}, nqy = {-qy, -qy}, nqz = {-qz, -qz};

  // pass 1: 8 macro-iters x 4 adjacent points per lane (packed fp32 math).
  // Per component: d = ((dx*dx + dy*dy) + dz*dz), dx = cx + (-qx) -- bit-exact
  // vs scalar __fsub_rn/__fmul_rn/__fadd_rn.
  f32x2 rd[8];                                // macro 0..3 -> 16 dists in regs
  float dmA = 3.4e38f, dmB = 3.4e38f;
#pragma unroll
  for (int it = 0; it < 8; ++it) {
    const int ofs = (it << 10) + (tid << 2);
    union { float4 f4; f32x2 h[2]; } X, Y, Z;
    X.f4 = *(const float4*)(Xb + ofs);
    Y.f4 = *(const float4*)(Yb + ofs);
    Z.f4 = *(const float4*)(Zb + ofs);
    const f32x2 dxl = pk_add(X.h[0], nqx), dyl = pk_add(Y.h[0], nqy),
                dzl = pk_add(Z.h[0], nqz);
    const f32x2 dxh = pk_add(X.h[1], nqx), dyh = pk_add(Y.h[1], nqy),
                dzh = pk_add(Z.h[1], nqz);
    const f32x2 sl =
        pk_add(pk_add(pk_mul(dxl, dxl), pk_mul(dyl, dyl)), pk_mul(dzl, dzl));
    const f32x2 sh =
        pk_add(pk_add(pk_mul(dxh, dxh), pk_mul(dyh, dyh)), pk_mul(dzh, dzh));
    dmA = fminf(fminf(sl.x, sl.y), dmA);      // v_min3_f32
    dmB = fminf(fminf(sh.x, sh.y), dmB);
    if (it < 4) {
      rd[it * 2] = sl;
      rd[it * 2 + 1] = sh;
    } else {
      union { float4 f4; f32x2 h[2]; } st;
      st.h[0] = sl;
      st.h[1] = sh;
      sdist4[((it - 4) << 8) + tid] = st.f4;   // one ds_write_b128
    }
  }
  float dmin = fminf(dmA, dmB);
  if (tid < 192) cands[tid] = ~0ULL;          // sentinel (> any real key)

  // pass 2: per-wave ascending bitonic sort of thread-mins; lane 7 holds the
  // wave's 8th-smallest. T = max over the 4 waves. Each wave has >=8
  // thread-mins <= T -> >=8 elements <= T per wave -> >=32 total -> T >= d32.
  float v = dmin;
#pragma unroll
  for (int k = 2; k <= 64; k <<= 1) {
#pragma unroll
    for (int j = k >> 1; j >= 1; j >>= 1) {
      const float o = __shfl_xor(v, j, 64);
      const bool dirAsc = ((lane & k) == 0);
      const bool lower = ((lane & j) == 0);
      const float lo = fminf(v, o), hi = fmaxf(v, o);
      v = (dirAsc == lower) ? lo : hi;
    }
  }
  if (lane == 7) sTw[w] = v;
  __syncthreads();
  const float T = fmaxf(fmaxf(sTw[0], sTw[1]), fmaxf(sTw[2], sTw[3]));

  // pass 3: wave-aggregated compaction (dist <= T) into this wave's 48-slot
  // region. ballot+mbcnt lane offsets; wbase is wave-uniform (scalar adds).
  // No LDS atomics -> no lgkm round-trip waits. E_w ~ E/4 ~ 14 << 48.
  int wbase = 0;
  const int cbase = w * 48;
#pragma unroll
  for (int t = 0; t < 8; ++t) {
    const int p0 = ((t >> 1) << 10) + (tid << 2) + ((t & 1) << 1);
#pragma unroll
    for (int c2 = 0; c2 < 2; ++c2) {
      const float d = (c2 == 0) ? rd[t].x : rd[t].y;
      const bool pr = (d <= T);
      const unsigned long long mk = __ballot(pr);
      if (pr) {
        const int mb = __builtin_amdgcn_mbcnt_hi(
            (unsigned int)(mk >> 32),
            __builtin_amdgcn_mbcnt_lo((unsigned int)mk, 0));
        const int pos = wbase + mb;
        if (pos < 48)
          cands[cbase + pos] =
              ((unsigned long long)__float_as_uint(d) << 32) |
              (unsigned int)(p0 + c2);
      }
      wbase += (int)__popcll(mk);
    }
  }
#pragma unroll
  for (int it = 4; it < 8; ++it) {
    const float4 d4 = sdist4[((it - 4) << 8) + tid];   // one ds_read_b128
    const int p0 = (it << 10) + (tid << 2);
    const float dd[4] = {d4.x, d4.y, d4.z, d4.w};
#pragma unroll
    for (int j = 0; j < 4; ++j) {
      const float d = dd[j];
      const bool pr = (d <= T);
      const unsigned long long mk = __ballot(pr);
      if (pr) {
        const int mb = __builtin_amdgcn_mbcnt_hi(
            (unsigned int)(mk >> 32),
            __builtin_amdgcn_mbcnt_lo((unsigned int)mk, 0));
        const int pos = wbase + mb;
        if (pos < 48)
          cands[cbase + pos] =
              ((unsigned long long)__float_as_uint(d) << 32) |
              (unsigned int)(p0 + j);
      }
      wbase += (int)__popcll(mk);
    }
  }
  __syncthreads();

  // pass 4: exact top-32 by rank-count over the sentinel-padded 192 slots.
  // Sentinels (~0ULL) never compare < key -> rank exact; real keys distinct
  // (idx in low bits) -> ranks are a permutation of 0..E-1; rank<32 writes.
  // Fixed bound + unroll -> pipelined broadcast ds_reads, no branchy waits.
  if (tid < 192) {
    const unsigned long long key = cands[tid];
    if (key != ~0ULL) {
      int rank = 0;
#pragma unroll 8
      for (int j = 0; j < 192; ++j) rank += (cands[j] < key) ? 1 : 0;
      if (rank < 32) knn[gid * 32 + rank] = (int)(unsigned int)key;
    }
  }
}

// ---------------- phase kernels: MFMA fused GEMMs ----------------------------
// Wave w owns cols 32w..32w+31. Per lane: m = lane&31 (A row / D col), q2 = lane>>5.
// A layout: A[m=lane&31][k=q2*8+j]; B layout: B^T[n=lane&31][k=q2*8+j];
// C/D layout: col=lane&31, row=(reg&3)+8*(reg>>2)+4*q2  [m74/m101-verified].
// Layer-1 is K=128: A = [sx bf16 (k<64) | d bf16 (k>=64)], B = full w1.
// XCD map: batch = blockIdx&7 (one 2MB x-slice per XCD L2).
// Pipeline: central row AND gather rows for g+1 prefetched into registers;
// raw s_barrier with lgkmcnt-only drain keeps those loads in flight.
// launch_bounds(256,2): 256 unified VGPR+AGPR per wave -> NO spills (R18).
template <int PHASE>
__global__ __launch_bounds__(256, 2) void kphase(
    const float* __restrict__ x, const int* __restrict__ indx,
    const int* __restrict__ knn, const float* __restrict__ b1,
    const unsigned short* __restrict__ w1b, const unsigned short* __restrict__ w2b,
    const float* __restrict__ b2, const float* __restrict__ st1,
    float* __restrict__ part, float* __restrict__ mout) {
  __shared__ __align__(16) unsigned short sxb[2][80];          // bf16 sx x2
  __shared__ __align__(16) unsigned short dls[2][32 * 68 + 8]; // d rows x2
  __shared__ __align__(16) unsigned short h1[PHASE == 2 ? 2 * 32 * 136 : 8];

  const int tid = threadIdx.x;
  const int w = tid >> 6;
  const int lane = tid & 63;
  const int m = lane & 31, q2 = lane >> 5;
  const int col = (w << 5) + m;              // output channel of this lane
  const int r8 = tid >> 3, c8 = (tid & 7) * 8;  // staging map: row, col-base

  const int bb = blockIdx.x & 7;             // batch == target XCD
  const int jj = blockIdx.x >> 3;            // 0..127 chunk within batch
  const float* xb = x + (size_t)bb * (N_ * 64);
  const int gidbase = (bb << 11) + jj * GPB_;
  const int sbase = jj * GPB_;

  // group-invariant operands in registers
  bf8 bf1[8];
#pragma unroll
  for (int t = 0; t < 8; ++t)
    bf1[t] = *(const bf8*)&w1b[col * 128 + t * 16 + q2 * 8];
  bf8 bf2[8];
  float s1 = 0.f, t1 = 0.f, b2v = 0.f;
  if constexpr (PHASE == 2) {
#pragma unroll
    for (int t = 0; t < 8; ++t)
      bf2[t] = *(const bf8*)&w2b[col * 128 + t * 16 + q2 * 8];
    s1 = st1[col];
    t1 = st1[128 + col];
    b2v = b2[col];
  }
  (void)w2b; (void)b2; (void)st1; (void)mout;
  const float b1c = b1[col];

  float sum = 0.f, ssq = 0.f;

  // pipeline prologue: central + gather rows for g=0 into regs; indices for g=1
  float4 ca_c, cc_c, ga_c, gc_c;
  {
    const int idx0 = indx[sbase];
    const int nbr0 = knn[(size_t)gidbase * 32 + r8];
    const float* c0 = xb + (size_t)idx0 * 64;
    ca_c = *(const float4*)(c0 + c8);
    cc_c = *(const float4*)(c0 + c8 + 4);
    const float* g0 = xb + (size_t)nbr0 * 64;
    ga_c = *(const float4*)(g0 + c8);
    gc_c = *(const float4*)(g0 + c8 + 4);
  }
  int idx_nxt = (GPB_ > 1) ? indx[sbase + 1] : 0;
  int nbr_nxt = (GPB_ > 1) ? knn[(size_t)(gidbase + 1) * 32 + r8] : 0;

#pragma unroll 1
  for (int g = 0; g < GPB_; ++g) {
    const int gid = gidbase + g;
    const int p = g & 1;

    // issue prefetch for g+1 rows FIRST (stays in flight across the barrier)
    float4 ca_n = ca_c, cc_n = cc_c, ga_n = ga_c, gc_n = gc_c;
    if (g + 1 < GPB_) {
      const float* cn = xb + (size_t)idx_nxt * 64;
      ca_n = *(const float4*)(cn + c8);
      cc_n = *(const float4*)(cn + c8 + 4);
      const float* gn = xb + (size_t)nbr_nxt * 64;
      ga_n = *(const float4*)(gn + c8);
      gc_n = *(const float4*)(gn + c8 + 4);
    }
    // indices for g+2 (consumed next iteration)
    if (g + 2 < GPB_) {
      nbr_nxt = knn[(size_t)(gid + 2) * 32 + r8];
      idx_nxt = indx[sbase + g + 2];
    }

    // stage d = x[nbr] - sx as bf16 into dls[p] (regs only; loaded last iter)
    {
      uint2 lo, hi;
      lo.x = bfpair(ga_c.x - ca_c.x, ga_c.y - ca_c.y);
      lo.y = bfpair(ga_c.z - ca_c.z, ga_c.w - ca_c.w);
      hi.x = bfpair(gc_c.x - cc_c.x, gc_c.y - cc_c.y);
      hi.y = bfpair(gc_c.z - cc_c.z, gc_c.w - cc_c.w);
      *(uint2*)&dls[p][r8 * 68 + c8] = lo;     // byte addr 136*r8+16k: 8B-aligned
      *(uint2*)&dls[p][r8 * 68 + c8 + 4] = hi;
    }
    if (tid < 8) {                             // tid<8: c8==tid*8 -> holds the
      uint2 lo, hi;                            // full central row in ca/cc
      lo.x = bfpair(ca_c.x, ca_c.y);
      lo.y = bfpair(ca_c.z, ca_c.w);
      hi.x = bfpair(cc_c.x, cc_c.y);
      hi.y = bfpair(cc_c.z, cc_c.w);
      *(uint2*)&sxb[p][tid * 8] = lo;
      *(uint2*)&sxb[p][tid * 8 + 4] = hi;
    }
    // LDS-visibility-only barrier: vmcnt NOT drained -> prefetch keeps flying
    asm volatile("s_waitcnt lgkmcnt(0)" ::: "memory");
    __builtin_amdgcn_s_barrier();

    // A-frags: t<4 from sxb[p] (k<64), t>=4 from dls[p] (k>=64)
    bf8 af[8];
#pragma unroll
    for (int t = 0; t < 4; ++t) {
      union { bf8 v; uint2 u[2]; } fa;
      fa.u[0] = *(const uint2*)&sxb[p][t * 16 + q2 * 8];
      fa.u[1] = *(const uint2*)&sxb[p][t * 16 + q2 * 8 + 4];
      af[t] = fa.v;
    }
#pragma unroll
    for (int t = 0; t < 4; ++t) {
      union { bf8 v; uint2 u[2]; } fa;
      fa.u[0] = *(const uint2*)&dls[p][m * 68 + t * 16 + q2 * 8];
      fa.u[1] = *(const uint2*)&dls[p][m * 68 + t * 16 + q2 * 8 + 4];
      af[4 + t] = fa.v;
    }

    f32x16 acc;
#pragma unroll
    for (int r = 0; r < 16; ++r) acc[r] = b1c;
#pragma unroll
    for (int t = 0; t < 8; ++t)
      acc = __builtin_amdgcn_mfma_f32_32x32x16_bf16(af[t], bf1[t], acc, 0, 0, 0);

    if constexpr (PHASE == 1) {
#pragma unroll
      for (int r = 0; r < 16; ++r) {
        const float v = acc[r];
        sum += v;
        ssq = fmaf(v, v, ssq);
      }
    } else {
      // bn1 + relu -> h1[p] bf16 in LDS (C-layout scatter, row stride 136)
      const int hp = p * (32 * 136);
#pragma unroll
      for (int r = 0; r < 16; ++r) {
        const float hv = fmaxf(0.f, fmaf(acc[r], s1, t1));
        const int row = (r & 3) + ((r >> 2) << 3) + (q2 << 2);
        h1[hp + row * 136 + col] = (unsigned short)bf1u(hv);
      }
      asm volatile("s_waitcnt lgkmcnt(0)" ::: "memory");
      __builtin_amdgcn_s_barrier();            // h1[p] ready (lgkm only)

      f32x16 acc2;
#pragma unroll
      for (int r = 0; r < 16; ++r) acc2[r] = b2v;
#pragma unroll
      for (int t = 0; t < 8; ++t) {
        const bf8 a2 = *(const bf8*)&h1[hp + m * 136 + t * 16 + q2 * 8];
        acc2 = __builtin_amdgcn_mfma_f32_32x32x16_bf16(a2, bf2[t], acc2, 0, 0, 0);
      }

      float mx = -1e30f;
#pragma unroll
      for (int r = 0; r < 16; ++r) {
        const float v = acc2[r];
        sum += v;
        ssq = fmaf(v, v, ssq);
        mx = fmaxf(mx, v);
      }
      mx = fmaxf(mx, __shfl_xor(mx, 32, 64));
      if (lane < 32) mout[(size_t)gid * 128 + col] = mx;
    }

    // rotate prefetched rows
    ca_c = ca_n;
    cc_c = cc_n;
    ga_c = ga_n;
    gc_c = gc_n;
  }

  // channel partials: each channel owned by exactly one wave
  sum += __shfl_xor(sum, 32, 64);
  ssq += __shfl_xor(ssq, 32, 64);
  if (lane < 32) {
    part[blockIdx.x * 256 + col] = sum;
    part[blockIdx.x * 256 + 128 + col] = ssq;
  }
}

// ---------------- stats reduce stage 1: 64 blocks, f64 partial sums ----------
__global__ __launch_bounds__(256) void kred1(const float* __restrict__ part,
                                             double* __restrict__ dbuf) {
  const int blk = blockIdx.x;                // 0..63: rows 16*blk..16*blk+15
  const int c = threadIdx.x;                 // 0..255 (128 sums | 128 ssqs)
  const float* p = part + (size_t)blk * 16 * 256 + c;
  double acc = 0.0;
#pragma unroll
  for (int r = 0; r < 16; ++r) acc += (double)p[r * 256];
  dbuf[blk * 256 + c] = acc;
}

// ---------------- stats reduce stage 2: finalize scale/shift -----------------
__global__ __launch_bounds__(256) void kred2(const double* __restrict__ dbuf,
                                             const float* __restrict__ gam,
                                             const float* __restrict__ bet,
                                             float* __restrict__ st) {
  __shared__ double sS[256];
  const int c = threadIdx.x;
  double acc = 0.0;
#pragma unroll 8
  for (int i = 0; i < 64; ++i) acc += dbuf[i * 256 + c];
  sS[c] = acc;
  __syncthreads();
  if (c < 128) {
    const double Sv = sS[c], SSv = sS[128 + c];
    const double cnt = 524288.0;             // B*S*K
    const double mean = Sv / cnt;
    const double var = SSv / cnt - mean * mean;
    const double scale = (double)gam[c] / sqrt(var + 1e-5);
    st[c] = (float)scale;
    st[128 + c] = (float)((double)bet[c] - mean * scale);
  }
}

// ---------------- final: out = relu(scale2 * max_k(y2) + shift2) -------------
__global__ __launch_bounds__(256) void kout(const float* __restrict__ m,
                                            const float* __restrict__ st2,
                                            float* __restrict__ out) {
  const int e4 = blockIdx.x * 256 + threadIdx.x;  // 524288 float4s
  const int o0 = (e4 & 31) * 4;
  const float4 v = ((const float4*)m)[e4];
  const float4 sc = *(const float4*)&st2[o0];
  const float4 sh = *(const float4*)&st2[128 + o0];
  float4 r;
  r.x = fmaxf(0.f, fmaf(v.x, sc.x, sh.x));
  r.y = fmaxf(0.f, fmaf(v.y, sc.y, sh.y));
  r.z = fmaxf(0.f, fmaf(v.z, sc.z, sh.z));
  r.w = fmaxf(0.f, fmaf(v.w, sc.w, sh.w));
  ((float4*)out)[e4] = r;
}

extern "C" void kernel_launch(void* const* d_in, const int* in_sizes, int n_in,
                              void* d_out, int out_size, void* d_ws, size_t ws_size,
                              hipStream_t stream) {
  (void)in_sizes; (void)n_in; (void)out_size; (void)ws_size;
  const float* x    = (const float*)d_in[0];
  const float* coor = (const float*)d_in[1];
  const int*   indx = (const int*)d_in[2];
  const float* w1   = (const float*)d_in[3];
  const float* b1   = (const float*)d_in[4];
  const float* g1   = (const float*)d_in[5];
  const float* be1  = (const float*)d_in[6];
  const float* w2   = (const float*)d_in[7];
  const float* b2   = (const float*)d_in[8];
  const float* g2   = (const float*)d_in[9];
  const float* be2  = (const float*)d_in[10];
  float* out = (float*)d_out;

  char* ws = (char*)d_ws;
  int*            knn   = (int*)(ws + 0);
  float*          mbuf  = (float*)(ws + 2097152);
  float*          part1 = (float*)(ws + 10485760);
  float*          soa   = (float*)(ws + 10485760); // aliases part1 (disjoint lifetime)
  float*          part2 = (float*)(ws + 12582912);
  unsigned short* w1b   = (unsigned short*)(ws + 14680064);
  unsigned short* w2b   = (unsigned short*)(ws + 14712832);
  float*          st1   = (float*)(ws + 14745600);
  float*          st2   = (float*)(ws + 14746624);
  double*         dbuf  = (double*)(ws + 14747648);

  float* outc = out + 2097152;   // sampled_coor region of d_out

  kprep<<<576, 256, 0, stream>>>(w1, w2, coor, indx, w1b, w2b, outc, soa);
  kknn<<<16384, 256, 0, stream>>>(soa, indx, knn);
  kphase<1><<<1024, 256, 0, stream>>>(x, indx, knn, b1, w1b, w2b, b2, nullptr,
                                      part1, nullptr);
  kred1<<<64, 256, 0, stream>>>(part1, dbuf);
  kred2<<<1, 256, 0, stream>>>(dbuf, g1, be1, st1);
  kphase<2><<<1024, 256, 0, stream>>>(x, indx, knn, b1, w1b, w2b, b2, st1,
                                      part2, mbuf);
  kred1<<<64, 256, 0, stream>>>(part2, dbuf);
  kred2<<<1, 256, 0, stream>>>(dbuf, g2, be2, st2);
  kout<<<2048, 256, 0, stream>>>(mbuf, st2, out);
}

// Round 7
// 239.687 us; speedup vs baseline: 1.0973x; 1.0973x over previous
//
#include <hip/hip_runtime.h>
#include <stdint.h>

// sample_and_group: B=8 N=8192 C=64 S=2048 K=32 OUT=128
// out = (out[8,2048,128], sampled_coor[8,2048,3]) concatenated in d_out (float32).
//
// R20: revert R19's kknn regression + one small trim.
//  - R19 post-mortem: ballot compaction ran ballot+mbcnt+popcount for ALL 32
//    checks/thread (~160 extra VALU) while the old atomicAdd only executed for
//    ~55 candidates per BLOCK (sparse predicate). Sentinel 192-scan similarly
//    3.5x the work of the E-bounded scan. VALUBusy 62->78% with dur 87->105us.
//    Both reverted to the R18 forms (atomicAdd + E-bounded rank scan).
//  - pass 2 trim: 32-wide bitonic (15 stages, was 21). T = max over 8
//    half-waves of the half-wave's 4th-smallest thread-min. Each half-wave
//    then has >=4 thread-mins <= T -> >=4 distinct elements <= T -> >=32
//    total -> T >= d32. Direction bit uses hl=lane&31 so both halves sort
//    ascending. E ~55-70, cap 192 unchanged.
//  - GPB=16 kept (R18->R19 total-delta attribution: neutral for kphase).
//
// Workspace layout (bytes):
//   [0,2MB)        knn indices  int32[16384*32]
//   [2MB,10MB)     m = max_k y2 f32[16384*128]
//   [10MB,11MB)    soa coords  f32[8][3][8192] (ALIASES part1; kknn-only lifetime)
//   [10MB,12MB)    partials1    f32[1024*256]
//   [12MB,14MB)    partials2    f32[1024*256]
//   [14MB,+32KB)   w1b  bf16 [o][k=0..127]
//   [..,+32KB)     w2b  bf16 [o][k=0..127]
//   [..,+1KB)      stats1 (scale[128], shift[128])
//   [..,+1KB)      stats2
//   [..,+128KB)    dbuf f64[64*256] (reduce stage-1 output)

#define N_    8192
#define GPB_  16      // groups per block in phase kernels

typedef __attribute__((ext_vector_type(8))) short bf8;
typedef __attribute__((ext_vector_type(16))) float f32x16;
typedef __attribute__((ext_vector_type(2))) float f32x2;

__device__ __forceinline__ unsigned int bf1u(float f) {   // RNE fp32->bf16 bits
  unsigned int u = __float_as_uint(f);
  return (u + 0x7fffu + ((u >> 16) & 1u)) >> 16;
}
__device__ __forceinline__ unsigned int bfpair(float lo, float hi) {
  return bf1u(lo) | (bf1u(hi) << 16);
}

// packed fp32 VOP3P helpers (CDNA: 2x fp32 per instruction, IEEE RN per lane)
__device__ __forceinline__ f32x2 pk_add(f32x2 a, f32x2 b) {
  f32x2 d;
  asm("v_pk_add_f32 %0, %1, %2" : "=v"(d) : "v"(a), "v"(b));
  return d;
}
__device__ __forceinline__ f32x2 pk_mul(f32x2 a, f32x2 b) {
  f32x2 d;
  asm("v_pk_mul_f32 %0, %1, %2" : "=v"(d) : "v"(a), "v"(b));
  return d;
}

// ---------------- prep: weight layouts + SoA coord pack + sampled_coor -------
__global__ __launch_bounds__(256) void kprep(const float* __restrict__ w1,
                                             const float* __restrict__ w2,
                                             const float* __restrict__ coor,
                                             const int* __restrict__ indx,
                                             unsigned short* __restrict__ w1b,
                                             unsigned short* __restrict__ w2b,
                                             float* __restrict__ outc,
                                             float* __restrict__ soa) {
  int e = blockIdx.x * 256 + threadIdx.x;   // grid is exactly 576*256 = 147456
  if (e < 16384) {                           // w1b[o][k] = bf16(w1[o][k])
    w1b[e] = (unsigned short)bf1u(w1[e]);
  } else if (e < 32768) {                    // w2b[o][k] = bf16(w2[o][k])
    int e2 = e - 16384;
    w2b[e2] = (unsigned short)bf1u(w2[e2]);
  } else if (e < 81920) {
    int e2 = e - 32768;                      // 0..49151 sampled_coor
    int bs = e2 / 3, c = e2 - bs * 3;
    int b = bs >> 11, s = bs & 2047;
    outc[e2] = coor[(b * N_ + indx[s]) * 3 + c];
  } else {
    int p = e - 81920;                       // 0..65535 SoA pack
    const int b = p >> 13, i = p & 8191;
    const float* src = coor + (size_t)p * 3;
    float* dst = soa + b * 24576;
    dst[i]         = src[0];
    dst[8192 + i]  = src[1];
    dst[16384 + i] = src[2];
  }
}

// ---------------- KNN: threshold-select, one query per 256-thread block -------
// Output = SET of 32 smallest keys (dist_bits<<32 | idx); order arbitrary
// (downstream max/mean/var are permutation-invariant over K).
// dist[macro 0..3] in registers, macro 4..7 in LDS; NO recompute.
__global__ __launch_bounds__(256, 8) void kknn(const float* __restrict__ soa,
                                               const int* __restrict__ indx,
                                               int* __restrict__ knn) {
  __shared__ __align__(16) float4 sdist4[4 * 256];  // 16KB: dist[it-4][tid] x4
  __shared__ float sTw[8];                    // per-half-wave 4th-smallest min
  __shared__ unsigned long long cands[192];
  __shared__ int ccnt;

  const int gid = blockIdx.x;
  const int b = gid >> 11, s = gid & 2047;
  const int tid = threadIdx.x;
  const int w = tid >> 6, lane = tid & 63;
  const int hl = lane & 31;                   // half-wave lane
  const float* Xb = soa + b * 24576;
  const float* Yb = Xb + 8192;
  const float* Zb = Xb + 16384;
  const int qi = indx[s];
  const float qx = Xb[qi], qy = Yb[qi], qz = Zb[qi];
  const f32x2 nqx = {-qx, -qx}, nqy = {-qy, -qy}, nqz = {-qz, -qz};

  // pass 1: 8 macro-iters x 4 adjacent points per lane (packed fp32 math).
  // Per component: d = ((dx*dx + dy*dy) + dz*dz), dx = cx + (-qx) -- bit-exact
  // vs scalar __fsub_rn/__fmul_rn/__fadd_rn.
  f32x2 rd[8];                                // macro 0..3 -> 16 dists in regs
  float dmA = 3.4e38f, dmB = 3.4e38f;
#pragma unroll
  for (int it = 0; it < 8; ++it) {
    const int ofs = (it << 10) + (tid << 2);
    union { float4 f4; f32x2 h[2]; } X, Y, Z;
    X.f4 = *(const float4*)(Xb + ofs);
    Y.f4 = *(const float4*)(Yb + ofs);
    Z.f4 = *(const float4*)(Zb + ofs);
    const f32x2 dxl = pk_add(X.h[0], nqx), dyl = pk_add(Y.h[0], nqy),
                dzl = pk_add(Z.h[0], nqz);
    const f32x2 dxh = pk_add(X.h[1], nqx), dyh = pk_add(Y.h[1], nqy),
                dzh = pk_add(Z.h[1], nqz);
    const f32x2 sl =
        pk_add(pk_add(pk_mul(dxl, dxl), pk_mul(dyl, dyl)), pk_mul(dzl, dzl));
    const f32x2 sh =
        pk_add(pk_add(pk_mul(dxh, dxh), pk_mul(dyh, dyh)), pk_mul(dzh, dzh));
    dmA = fminf(fminf(sl.x, sl.y), dmA);      // v_min3_f32
    dmB = fminf(fminf(sh.x, sh.y), dmB);
    if (it < 4) {
      rd[it * 2] = sl;
      rd[it * 2 + 1] = sh;
    } else {
      union { float4 f4; f32x2 h[2]; } st;
      st.h[0] = sl;
      st.h[1] = sh;
      sdist4[((it - 4) << 8) + tid] = st.f4;   // one ds_write_b128
    }
  }
  float dmin = fminf(dmA, dmB);
  if (tid == 0) ccnt = 0;
  if (tid < 192) cands[tid] = ~0ULL;

  // pass 2: per-HALF-WAVE ascending bitonic sort (32 elements, 15 stages;
  // direction from hl=lane&31 so both halves sort ascending). Lane hl==3
  // holds the half-wave's 4th-smallest thread-min. T = max over the 8
  // half-waves. Each half-wave has >=4 thread-mins <= T -> >=4 distinct
  // elements <= T -> >=32 total -> T >= d32.
  float v = dmin;
#pragma unroll
  for (int k = 2; k <= 32; k <<= 1) {
#pragma unroll
    for (int j = k >> 1; j >= 1; j >>= 1) {
      const float o = __shfl_xor(v, j, 64);
      const bool dirAsc = ((hl & k) == 0);
      const bool lower = ((hl & j) == 0);
      const float lo = fminf(v, o), hi = fmaxf(v, o);
      v = (dirAsc == lower) ? lo : hi;
    }
  }
  if (hl == 3) sTw[(w << 1) + (lane >> 5)] = v;
  __syncthreads();
  const float T =
      fmaxf(fmaxf(fmaxf(sTw[0], sTw[1]), fmaxf(sTw[2], sTw[3])),
            fmaxf(fmaxf(sTw[4], sTw[5]), fmaxf(sTw[6], sTw[7])));

  // pass 3: compact candidates (dist <= T) from regs + LDS; E~55-70, cap 192.
  // Sparse predicate -> per-lane atomicAdd is cheaper than wave aggregation
  // (R19 post-mortem).
#pragma unroll
  for (int t = 0; t < 8; ++t) {
    const int p0 = ((t >> 1) << 10) + (tid << 2) + ((t & 1) << 1);
    const float d0 = rd[t].x, d1 = rd[t].y;
    if (d0 <= T) {
      const int pos = atomicAdd(&ccnt, 1);
      if (pos < 192)
        cands[pos] = ((unsigned long long)__float_as_uint(d0) << 32) |
                     (unsigned int)p0;
    }
    if (d1 <= T) {
      const int pos = atomicAdd(&ccnt, 1);
      if (pos < 192)
        cands[pos] = ((unsigned long long)__float_as_uint(d1) << 32) |
                     (unsigned int)(p0 + 1);
    }
  }
#pragma unroll
  for (int it = 4; it < 8; ++it) {
    const float4 d4 = sdist4[((it - 4) << 8) + tid];   // one ds_read_b128
    const int p0 = (it << 10) + (tid << 2);
    const float dd[4] = {d4.x, d4.y, d4.z, d4.w};
#pragma unroll
    for (int j = 0; j < 4; ++j) {
      if (dd[j] <= T) {
        const int pos = atomicAdd(&ccnt, 1);
        if (pos < 192)
          cands[pos] = ((unsigned long long)__float_as_uint(dd[j]) << 32) |
                       (unsigned int)(p0 + j);
      }
    }
  }
  __syncthreads();

  // pass 4: exact top-32 of E candidates by rank-count. Keys are distinct
  // (idx in low bits) so ranks 0..E-1 are a permutation; rank<32 writes.
  // LDS reads are wave-uniform (broadcast); no cross-lane chains.
  const int E = min(ccnt, 192);               // E >= 32 guaranteed
  if (tid < E) {
    const unsigned long long key = cands[tid];
    int rank = 0;
    for (int j = 0; j < E; ++j) rank += (cands[j] < key) ? 1 : 0;
    if (rank < 32) knn[gid * 32 + rank] = (int)(unsigned int)key;
  }
}

// ---------------- phase kernels: MFMA fused GEMMs ----------------------------
// Wave w owns cols 32w..32w+31. Per lane: m = lane&31 (A row / D col), q2 = lane>>5.
// A layout: A[m=lane&31][k=q2*8+j]; B layout: B^T[n=lane&31][k=q2*8+j];
// C/D layout: col=lane&31, row=(reg&3)+8*(reg>>2)+4*q2  [m74/m101-verified].
// Layer-1 is K=128: A = [sx bf16 (k<64) | d bf16 (k>=64)], B = full w1.
// XCD map: batch = blockIdx&7 (one 2MB x-slice per XCD L2).
// Pipeline: central row AND gather rows for g+1 prefetched into registers;
// raw s_barrier with lgkmcnt-only drain keeps those loads in flight.
// launch_bounds(256,2): 256 unified VGPR+AGPR per wave -> NO spills (R18).
template <int PHASE>
__global__ __launch_bounds__(256, 2) void kphase(
    const float* __restrict__ x, const int* __restrict__ indx,
    const int* __restrict__ knn, const float* __restrict__ b1,
    const unsigned short* __restrict__ w1b, const unsigned short* __restrict__ w2b,
    const float* __restrict__ b2, const float* __restrict__ st1,
    float* __restrict__ part, float* __restrict__ mout) {
  __shared__ __align__(16) unsigned short sxb[2][80];          // bf16 sx x2
  __shared__ __align__(16) unsigned short dls[2][32 * 68 + 8]; // d rows x2
  __shared__ __align__(16) unsigned short h1[PHASE == 2 ? 2 * 32 * 136 : 8];

  const int tid = threadIdx.x;
  const int w = tid >> 6;
  const int lane = tid & 63;
  const int m = lane & 31, q2 = lane >> 5;
  const int col = (w << 5) + m;              // output channel of this lane
  const int r8 = tid >> 3, c8 = (tid & 7) * 8;  // staging map: row, col-base

  const int bb = blockIdx.x & 7;             // batch == target XCD
  const int jj = blockIdx.x >> 3;            // 0..127 chunk within batch
  const float* xb = x + (size_t)bb * (N_ * 64);
  const int gidbase = (bb << 11) + jj * GPB_;
  const int sbase = jj * GPB_;

  // group-invariant operands in registers
  bf8 bf1[8];
#pragma unroll
  for (int t = 0; t < 8; ++t)
    bf1[t] = *(const bf8*)&w1b[col * 128 + t * 16 + q2 * 8];
  bf8 bf2[8];
  float s1 = 0.f, t1 = 0.f, b2v = 0.f;
  if constexpr (PHASE == 2) {
#pragma unroll
    for (int t = 0; t < 8; ++t)
      bf2[t] = *(const bf8*)&w2b[col * 128 + t * 16 + q2 * 8];
    s1 = st1[col];
    t1 = st1[128 + col];
    b2v = b2[col];
  }
  (void)w2b; (void)b2; (void)st1; (void)mout;
  const float b1c = b1[col];

  float sum = 0.f, ssq = 0.f;

  // pipeline prologue: central + gather rows for g=0 into regs; indices for g=1
  float4 ca_c, cc_c, ga_c, gc_c;
  {
    const int idx0 = indx[sbase];
    const int nbr0 = knn[(size_t)gidbase * 32 + r8];
    const float* c0 = xb + (size_t)idx0 * 64;
    ca_c = *(const float4*)(c0 + c8);
    cc_c = *(const float4*)(c0 + c8 + 4);
    const float* g0 = xb + (size_t)nbr0 * 64;
    ga_c = *(const float4*)(g0 + c8);
    gc_c = *(const float4*)(g0 + c8 + 4);
  }
  int idx_nxt = (GPB_ > 1) ? indx[sbase + 1] : 0;
  int nbr_nxt = (GPB_ > 1) ? knn[(size_t)(gidbase + 1) * 32 + r8] : 0;

#pragma unroll 1
  for (int g = 0; g < GPB_; ++g) {
    const int gid = gidbase + g;
    const int p = g & 1;

    // issue prefetch for g+1 rows FIRST (stays in flight across the barrier)
    float4 ca_n = ca_c, cc_n = cc_c, ga_n = ga_c, gc_n = gc_c;
    if (g + 1 < GPB_) {
      const float* cn = xb + (size_t)idx_nxt * 64;
      ca_n = *(const float4*)(cn + c8);
      cc_n = *(const float4*)(cn + c8 + 4);
      const float* gn = xb + (size_t)nbr_nxt * 64;
      ga_n = *(const float4*)(gn + c8);
      gc_n = *(const float4*)(gn + c8 + 4);
    }
    // indices for g+2 (consumed next iteration)
    if (g + 2 < GPB_) {
      nbr_nxt = knn[(size_t)(gid + 2) * 32 + r8];
      idx_nxt = indx[sbase + g + 2];
    }

    // stage d = x[nbr] - sx as bf16 into dls[p] (regs only; loaded last iter)
    {
      uint2 lo, hi;
      lo.x = bfpair(ga_c.x - ca_c.x, ga_c.y - ca_c.y);
      lo.y = bfpair(ga_c.z - ca_c.z, ga_c.w - ca_c.w);
      hi.x = bfpair(gc_c.x - cc_c.x, gc_c.y - cc_c.y);
      hi.y = bfpair(gc_c.z - cc_c.z, gc_c.w - cc_c.w);
      *(uint2*)&dls[p][r8 * 68 + c8] = lo;     // byte addr 136*r8+16k: 8B-aligned
      *(uint2*)&dls[p][r8 * 68 + c8 + 4] = hi;
    }
    if (tid < 8) {                             // tid<8: c8==tid*8 -> holds the
      uint2 lo, hi;                            // full central row in ca/cc
      lo.x = bfpair(ca_c.x, ca_c.y);
      lo.y = bfpair(ca_c.z, ca_c.w);
      hi.x = bfpair(cc_c.x, cc_c.y);
      hi.y = bfpair(cc_c.z, cc_c.w);
      *(uint2*)&sxb[p][tid * 8] = lo;
      *(uint2*)&sxb[p][tid * 8 + 4] = hi;
    }
    // LDS-visibility-only barrier: vmcnt NOT drained -> prefetch keeps flying
    asm volatile("s_waitcnt lgkmcnt(0)" ::: "memory");
    __builtin_amdgcn_s_barrier();

    // A-frags: t<4 from sxb[p] (k<64), t>=4 from dls[p] (k>=64)
    bf8 af[8];
#pragma unroll
    for (int t = 0; t < 4; ++t) {
      union { bf8 v; uint2 u[2]; } fa;
      fa.u[0] = *(const uint2*)&sxb[p][t * 16 + q2 * 8];
      fa.u[1] = *(const uint2*)&sxb[p][t * 16 + q2 * 8 + 4];
      af[t] = fa.v;
    }
#pragma unroll
    for (int t = 0; t < 4; ++t) {
      union { bf8 v; uint2 u[2]; } fa;
      fa.u[0] = *(const uint2*)&dls[p][m * 68 + t * 16 + q2 * 8];
      fa.u[1] = *(const uint2*)&dls[p][m * 68 + t * 16 + q2 * 8 + 4];
      af[4 + t] = fa.v;
    }

    f32x16 acc;
#pragma unroll
    for (int r = 0; r < 16; ++r) acc[r] = b1c;
#pragma unroll
    for (int t = 0; t < 8; ++t)
      acc = __builtin_amdgcn_mfma_f32_32x32x16_bf16(af[t], bf1[t], acc, 0, 0, 0);

    if constexpr (PHASE == 1) {
#pragma unroll
      for (int r = 0; r < 16; ++r) {
        const float v = acc[r];
        sum += v;
        ssq = fmaf(v, v, ssq);
      }
    } else {
      // bn1 + relu -> h1[p] bf16 in LDS (C-layout scatter, row stride 136)
      const int hp = p * (32 * 136);
#pragma unroll
      for (int r = 0; r < 16; ++r) {
        const float hv = fmaxf(0.f, fmaf(acc[r], s1, t1));
        const int row = (r & 3) + ((r >> 2) << 3) + (q2 << 2);
        h1[hp + row * 136 + col] = (unsigned short)bf1u(hv);
      }
      asm volatile("s_waitcnt lgkmcnt(0)" ::: "memory");
      __builtin_amdgcn_s_barrier();            // h1[p] ready (lgkm only)

      f32x16 acc2;
#pragma unroll
      for (int r = 0; r < 16; ++r) acc2[r] = b2v;
#pragma unroll
      for (int t = 0; t < 8; ++t) {
        const bf8 a2 = *(const bf8*)&h1[hp + m * 136 + t * 16 + q2 * 8];
        acc2 = __builtin_amdgcn_mfma_f32_32x32x16_bf16(a2, bf2[t], acc2, 0, 0, 0);
      }

      float mx = -1e30f;
#pragma unroll
      for (int r = 0; r < 16; ++r) {
        const float v = acc2[r];
        sum += v;
        ssq = fmaf(v, v, ssq);
        mx = fmaxf(mx, v);
      }
      mx = fmaxf(mx, __shfl_xor(mx, 32, 64));
      if (lane < 32) mout[(size_t)gid * 128 + col] = mx;
    }

    // rotate prefetched rows
    ca_c = ca_n;
    cc_c = cc_n;
    ga_c = ga_n;
    gc_c = gc_n;
  }

  // channel partials: each channel owned by exactly one wave
  sum += __shfl_xor(sum, 32, 64);
  ssq += __shfl_xor(ssq, 32, 64);
  if (lane < 32) {
    part[blockIdx.x * 256 + col] = sum;
    part[blockIdx.x * 256 + 128 + col] = ssq;
  }
}

// ---------------- stats reduce stage 1: 64 blocks, f64 partial sums ----------
__global__ __launch_bounds__(256) void kred1(const float* __restrict__ part,
                                             double* __restrict__ dbuf) {
  const int blk = blockIdx.x;                // 0..63: rows 16*blk..16*blk+15
  const int c = threadIdx.x;                 // 0..255 (128 sums | 128 ssqs)
  const float* p = part + (size_t)blk * 16 * 256 + c;
  double acc = 0.0;
#pragma unroll
  for (int r = 0; r < 16; ++r) acc += (double)p[r * 256];
  dbuf[blk * 256 + c] = acc;
}

// ---------------- stats reduce stage 2: finalize scale/shift -----------------
__global__ __launch_bounds__(256) void kred2(const double* __restrict__ dbuf,
                                             const float* __restrict__ gam,
                                             const float* __restrict__ bet,
                                             float* __restrict__ st) {
  __shared__ double sS[256];
  const int c = threadIdx.x;
  double acc = 0.0;
#pragma unroll 8
  for (int i = 0; i < 64; ++i) acc += dbuf[i * 256 + c];
  sS[c] = acc;
  __syncthreads();
  if (c < 128) {
    const double Sv = sS[c], SSv = sS[128 + c];
    const double cnt = 524288.0;             // B*S*K
    const double mean = Sv / cnt;
    const double var = SSv / cnt - mean * mean;
    const double scale = (double)gam[c] / sqrt(var + 1e-5);
    st[c] = (float)scale;
    st[128 + c] = (float)((double)bet[c] - mean * scale);
  }
}

// ---------------- final: out = relu(scale2 * max_k(y2) + shift2) -------------
__global__ __launch_bounds__(256) void kout(const float* __restrict__ m,
                                            const float* __restrict__ st2,
                                            float* __restrict__ out) {
  const int e4 = blockIdx.x * 256 + threadIdx.x;  // 524288 float4s
  const int o0 = (e4 & 31) * 4;
  const float4 v = ((const float4*)m)[e4];
  const float4 sc = *(const float4*)&st2[o0];
  const float4 sh = *(const float4*)&st2[128 + o0];
  float4 r;
  r.x = fmaxf(0.f, fmaf(v.x, sc.x, sh.x));
  r.y = fmaxf(0.f, fmaf(v.y, sc.y, sh.y));
  r.z = fmaxf(0.f, fmaf(v.z, sc.z, sh.z));
  r.w = fmaxf(0.f, fmaf(v.w, sc.w, sh.w));
  ((float4*)out)[e4] = r;
}

extern "C" void kernel_launch(void* const* d_in, const int* in_sizes, int n_in,
                              void* d_out, int out_size, void* d_ws, size_t ws_size,
                              hipStream_t stream) {
  (void)in_sizes; (void)n_in; (void)out_size; (void)ws_size;
  const float* x    = (const float*)d_in[0];
  const float* coor = (const float*)d_in[1];
  const int*   indx = (const int*)d_in[2];
  const float* w1   = (const float*)d_in[3];
  const float* b1   = (const float*)d_in[4];
  const float* g1   = (const float*)d_in[5];
  const float* be1  = (const float*)d_in[6];
  const float* w2   = (const float*)d_in[7];
  const float* b2   = (const float*)d_in[8];
  const float* g2   = (const float*)d_in[9];
  const float* be2  = (const float*)d_in[10];
  float* out = (float*)d_out;

  char* ws = (char*)d_ws;
  int*            knn   = (int*)(ws + 0);
  float*          mbuf  = (float*)(ws + 2097152);
  float*          part1 = (float*)(ws + 10485760);
  float*          soa   = (float*)(ws + 10485760); // aliases part1 (disjoint lifetime)
  float*          part2 = (float*)(ws + 12582912);
  unsigned short* w1b   = (unsigned short*)(ws + 14680064);
  unsigned short* w2b   = (unsigned short*)(ws + 14712832);
  float*          st1   = (float*)(ws + 14745600);
  float*          st2   = (float*)(ws + 14746624);
  double*         dbuf  = (double*)(ws + 14747648);

  float* outc = out + 2097152;   // sampled_coor region of d_out

  kprep<<<576, 256, 0, stream>>>(w1, w2, coor, indx, w1b, w2b, outc, soa);
  kknn<<<16384, 256, 0, stream>>>(soa, indx, knn);
  kphase<1><<<1024, 256, 0, stream>>>(x, indx, knn, b1, w1b, w2b, b2, nullptr,
                                      part1, nullptr);
  kred1<<<64, 256, 0, stream>>>(part1, dbuf);
  kred2<<<1, 256, 0, stream>>>(dbuf, g1, be1, st1);
  kphase<2><<<1024, 256, 0, stream>>>(x, indx, knn, b1, w1b, w2b, b2, st1,
                                      part2, mbuf);
  kred1<<<64, 256, 0, stream>>>(part2, dbuf);
  kred2<<<1, 256, 0, stream>>>(dbuf, g2, be2, st2);
  kout<<<2048, 256, 0, stream>>>(mbuf, st2, out);
}